// Round 1
// 1160.213 us; speedup vs baseline: 1.8914x; 1.8914x over previous
//
#include <hip/hip_runtime.h>

// Problem constants
#define BSZ  128
#define TT   50
#define CIN  2312
#define HID  300
#define NOUT 10
#define KS   5
#define T1   51          // (TT+5) - KS + 1
#define T2   52          // (T1+5) - KS + 1

typedef unsigned int u32;

// exp(-k^2/8) constants, k=1..4 (fp32)
#define EK1f 0.88249690258459546f
#define EK2f 0.60653065971263342f
#define EK3f 0.32465246735834974f
#define EK4f 0.13533528323661270f

// ---------------------------------------------------------------------------
// Layer-1 tile for (batch b, o-tile ow): fp32 GEMM 64t(51 valid) x 64o over
// K = CIN*KS, with per-chunk (40-term) fp32 partials promoted into an fp64
// accumulator (error ~1e-7 << JAX fp32's own ~1e-6 — spike decisions safe).
// A staged ONCE as a 55-slot time window shared by all 5 taps.
// Gauss weights synthesized in fp32 (hw v_exp_f32) into a 72-padded LDS
// layout: B-writes 2-way (free), B-reads conflict-free float2.
// Global loads for chunk i+1 are issued right after the stage barrier and
// consumed at the next iteration's LDS-write, so GEMM hides their latency.
// LDS (dsm = 3264 doubles = 26112 B):
//   Bsf float[5*8][72] at float-offset 0     (2880 floats)
//   As  float[8][80]   at float-offset 2880  ( 640 floats)
//   y1s double[51][64] overlays [0,3264) doubles after the final sync.
// ---------------------------------------------------------------------------
__device__ __forceinline__ void layer1_tile(
    int b, int ow, int tid,
    const float* __restrict__ data, const float* __restrict__ W1,
    const float* __restrict__ P1, const float* __restrict__ b1v,
    double* __restrict__ dsm, u32* __restrict__ bits)
{
  float* Bsf = (float*)dsm;          // [k*8+isub][72]
  float* As  = (float*)dsm + 2880;   // [isub][80] slots

  const int ty = tid >> 5;           // 0..7  -> rows 8ty..+7
  const int tx = tid & 31;           // 0..31 -> cols 2tx..+1
  const int r0 = ty << 3;
  const int c0 = tx << 1;

  const float* abase = data + (size_t)b * (TT * CIN);

  // stage-A per-thread constants (tid < 220 active)
  const int slot = tid >> 2;         // 0..54
  const int pair = tid & 3;          // 0..3 -> i-subs 2p,2p+1
  const int tp   = slot - 5;         // -5..49 (< TT always)

  // stage-B per-thread constants: 2 cells, u = tid and tid+256
  const int isub = tid & 7;
  const int oA = tid >> 3;           // 0..31  -> bo <= 287 < HID, always valid
  const int oB = oA + 32;            // 32..63 -> bo can reach 319 (guard)
  const int boA = ow * 64 + oA;
  const int boB = ow * 64 + oB;
  const bool vB = boB < HID;

  double acc[8][2];
#pragma unroll
  for (int r = 0; r < 8; ++r) { acc[r][0] = 0.0; acc[r][1] = 0.0; }

  // ---- prefetch chunk 0 into registers ----
  float2 aA = make_float2(0.f, 0.f);
  float wA = 0.f, pA = 0.f, wB = 0.f, pB = 0.f;
  if (tid < 220 && tp >= 0)
    aA = *(const float2*)(abase + (size_t)tp * CIN + 2 * pair);
  wA = W1[(size_t)boA * CIN + isub];
  pA = P1[(size_t)boA * CIN + isub];
  if (vB) {
    wB = W1[(size_t)boB * CIN + isub];
    pB = P1[(size_t)boB * CIN + isub];
  }

  for (int i0 = 0; i0 < CIN; i0 += 8) {            // 289 chunks exactly
    // ---- stage A from regs: one 55-slot time window, fp32 ----
    if (tid < 220) {
      As[(2 * pair) * 80 + slot]     = aA.x;
      As[(2 * pair + 1) * 80 + slot] = aA.y;
    }
    // ---- stage B from regs: synthesize 5 gauss taps in fp32 ----
    {
      const float c  = pA + 2.0f;                  // P + MAX_DELAY//2
      const float E0 = __expf(-0.125f * c * c);
      const float U  = __expf(0.25f * c);
      const float u2 = U * U;
      const float e0 = E0;
      const float e1 = E0 * U * EK1f;
      const float e2 = E0 * u2 * EK2f;
      const float e3 = E0 * (u2 * U) * EK3f;
      const float e4 = E0 * (u2 * u2) * EK4f;
      const float inv = 1.0f / (((((e0 + e1) + e2) + e3) + e4) + 1e-7f);
      float* bp = Bsf + isub * 72 + oA;
      bp[0]    = wA * (e0 * inv);
      bp[576]  = wA * (e1 * inv);
      bp[1152] = wA * (e2 * inv);
      bp[1728] = wA * (e3 * inv);
      bp[2304] = wA * (e4 * inv);
    }
    {
      const float c  = pB + 2.0f;
      const float E0 = __expf(-0.125f * c * c);
      const float U  = __expf(0.25f * c);
      const float u2 = U * U;
      const float e0 = E0;
      const float e1 = E0 * U * EK1f;
      const float e2 = E0 * u2 * EK2f;
      const float e3 = E0 * (u2 * U) * EK3f;
      const float e4 = E0 * (u2 * u2) * EK4f;
      const float inv = 1.0f / (((((e0 + e1) + e2) + e3) + e4) + 1e-7f);
      float* bp = Bsf + isub * 72 + oB;
      bp[0]    = wB * (e0 * inv);
      bp[576]  = wB * (e1 * inv);
      bp[1152] = wB * (e2 * inv);
      bp[1728] = wB * (e3 * inv);
      bp[2304] = wB * (e4 * inv);
    }
    __syncthreads();

    // ---- issue next chunk's global loads (latency hidden by GEMM) ----
    const int i0n = i0 + 8;
    if (i0n < CIN) {
      if (tid < 220 && tp >= 0)
        aA = *(const float2*)(abase + (size_t)tp * CIN + i0n + 2 * pair);
      wA = W1[(size_t)boA * CIN + i0n + isub];
      pA = P1[(size_t)boA * CIN + i0n + isub];
      if (vB) {
        wB = W1[(size_t)boB * CIN + i0n + isub];
        pB = P1[(size_t)boB * CIN + i0n + isub];
      }
    }

    // ---- compute: 8 i-steps x 5 taps x (8x2) micro-tile, fp32 ----
    float accf[8][2];
#pragma unroll
    for (int r = 0; r < 8; ++r) { accf[r][0] = 0.f; accf[r][1] = 0.f; }
#pragma unroll
    for (int kk = 0; kk < 8; ++kk) {
      const float* ap = &As[kk * 80 + r0];         // slots r0..r0+11 (aligned)
      const float4 a0 = *(const float4*)(ap);
      const float4 a1 = *(const float4*)(ap + 4);
      const float4 a2 = *(const float4*)(ap + 8);
      float av[12];
      av[0] = a0.x; av[1] = a0.y; av[2]  = a0.z; av[3]  = a0.w;
      av[4] = a1.x; av[5] = a1.y; av[6]  = a1.z; av[7]  = a1.w;
      av[8] = a2.x; av[9] = a2.y; av[10] = a2.z; av[11] = a2.w;
      float bv[KS][2];
#pragma unroll
      for (int k = 0; k < KS; ++k) {
        const float2 bb = *(const float2*)&Bsf[(k * 8 + kk) * 72 + c0];
        bv[k][0] = bb.x; bv[k][1] = bb.y;
      }
#pragma unroll
      for (int k = 0; k < KS; ++k)
#pragma unroll
        for (int r = 0; r < 8; ++r) {
          accf[r][0] = fmaf(av[r + k], bv[k][0], accf[r][0]);
          accf[r][1] = fmaf(av[r + k], bv[k][1], accf[r][1]);
        }
    }
    // promote 40-term fp32 partial into fp64 accumulator
#pragma unroll
    for (int r = 0; r < 8; ++r) {
      acc[r][0] += (double)accf[r][0];
      acc[r][1] += (double)accf[r][1];
    }
    __syncthreads();
  }

  // ---- y1 tile -> LDS (overlays Bsf/As; fenced by loop-final sync) ----
  double* y1s = dsm;                               // [t][64], t<51
#pragma unroll
  for (int r = 0; r < 8; ++r) {
    const int t = r0 + r;
    if (t < T1) {
      y1s[t * 64 + c0]     = acc[r][0];
      y1s[t * 64 + c0 + 1] = acc[r][1];
    }
  }
  __syncthreads();

  // ---- fp64 LIF scan on wave 0 + ballot bit-pack ----
  if (tid < 64) {
    const int o = ow * 64 + tid;
    const bool valid = o < HID;
    const double bias = valid ? (double)b1v[o] : 0.0;
    double mem = 0.0;
    for (int t = 0; t < T1; ++t) {
      const double x = y1s[t * 64 + tid] + bias;
      const double reset = (mem > 1.0) ? 1.0 : 0.0;
      mem = __dsub_rn(__dadd_rn(__dmul_rn(0.9, mem), x), reset);
      const unsigned long long mk = __ballot(valid && (mem > 1.0));
      if (tid == 0)  bits[t * 10 + 2 * ow]     = (u32)mk;
      if (tid == 32) bits[t * 10 + 2 * ow + 1] = (u32)(mk >> 32);
    }
  }
  __syncthreads();
}

// ---------------------------------------------------------------------------
// Layer-2 conv + LIF2 (fp32), spike bits already in LDS at smem+15000.
// smem floats: [0,15000) K2s [o][k][i], [15000,15510) lbits u32,
// [15510,16030) y2s [t2][o].
// ---------------------------------------------------------------------------
__device__ __forceinline__ void layer2_lif2(
    int b, int tid, float* smem,
    const float* __restrict__ W2, const float* __restrict__ P2,
    const float* __restrict__ b2, float* __restrict__ out)
{
  float* K2s = smem;
  const u32* lbits = (const u32*)(smem + 15000);
  float* y2s = smem + 15510;

  for (int idx = tid; idx < NOUT * HID; idx += 256) {
    const int o = idx / HID, i = idx % HID;
    const float w = W2[idx], p = P2[idx];
    const float c = p + 2.0f;
    float e[KS], s = 0.f;
#pragma unroll
    for (int k = 0; k < KS; ++k) {
      const float d = ((float)k - c) * 0.5f;
      e[k] = __expf(-0.5f * d * d);
      s += e[k];
    }
    const float denom = s + 1e-7f;
#pragma unroll
    for (int k = 0; k < KS; ++k)
      K2s[(o * KS + k) * HID + i] = w * (e[k] / denom);
  }
  __syncthreads();                    // also fences lbits population

  for (int task = tid; task < T2 * NOUT; task += 256) {
    const int t2 = task / NOUT, o = task % NOUT;
    float acc = b2[o];
#pragma unroll
    for (int k = 0; k < KS; ++k) {
      const int tp = t2 + k - KS;
      if (tp < 0 || tp >= T1) continue;
      const float* kr = K2s + (o * KS + k) * HID;
      const u32* br = lbits + tp * 10;
      for (int i = 0; i < HID; ++i)
        acc = fmaf((float)((br[i >> 5] >> (i & 31)) & 1u), kr[i], acc);
    }
    y2s[task] = acc;
  }
  __syncthreads();

  if (tid < NOUT) {
    float mem = 0.f;
    for (int t = 0; t < T2; ++t) {
      const float x = y2s[t * NOUT + tid];
      const float reset = (mem > 1.0f) ? 1.0f : 0.0f;
      mem = __fsub_rn(__fadd_rn(__fmul_rn(0.9f, mem), x), reset);
      out[(size_t)t * (BSZ * NOUT) + b * NOUT + tid] = (mem > 1.0f) ? 1.0f : 0.0f;
      out[(size_t)T2 * BSZ * NOUT + (size_t)t * (BSZ * NOUT) + b * NOUT + tid] = mem;
    }
  }
}

// ---------------- split path ------------------------------------------------
__global__ __launch_bounds__(256) void snn_l1(
    const float* __restrict__ data, const float* __restrict__ W1,
    const float* __restrict__ P1, const float* __restrict__ b1v,
    u32* __restrict__ gbits)
{
  __shared__ double dsm[3264];       // 26112 B
  const int ow = blockIdx.x, b = blockIdx.y;
  layer1_tile(b, ow, threadIdx.x, data, W1, P1, b1v, dsm,
              gbits + (size_t)b * 510);
}

__global__ __launch_bounds__(256) void snn_l2k(
    const u32* __restrict__ gbits,
    const float* __restrict__ W2, const float* __restrict__ P2,
    const float* __restrict__ b2, float* __restrict__ out)
{
  __shared__ float smem[16030];      // 64120 B
  const int b = blockIdx.x, tid = threadIdx.x;
  u32* lbits = (u32*)(smem + 15000);
  for (int i = tid; i < 510; i += 256) lbits[i] = gbits[(size_t)b * 510 + i];
  layer2_lif2(b, tid, smem, W2, P2, b2, out);
}

// ---------------- zero-workspace fallback -----------------------------------
__global__ __launch_bounds__(256) void snn_mono(
    const float* __restrict__ data, const float* __restrict__ W1,
    const float* __restrict__ P1, const float* __restrict__ b1v,
    const float* __restrict__ W2, const float* __restrict__ P2,
    const float* __restrict__ b2, float* __restrict__ out)
{
  __shared__ double dsm[8015];       // 64120 B; layer1 uses [0,3264)
  const int b = blockIdx.x, tid = threadIdx.x;
  u32* lbits = (u32*)((float*)dsm + 15000);   // float-offset 15000 = byte 60000
  for (int ow = 0; ow < 5; ++ow)
    layer1_tile(b, ow, tid, data, W1, P1, b1v, dsm, lbits);
  layer2_lif2(b, tid, (float*)dsm, W2, P2, b2, out);
}

// ---------------- launcher --------------------------------------------------
extern "C" void kernel_launch(void* const* d_in, const int* in_sizes, int n_in,
                              void* d_out, int out_size, void* d_ws, size_t ws_size,
                              hipStream_t stream) {
  const float* data = (const float*)d_in[0];
  const float* W1   = (const float*)d_in[1];
  const float* P1   = (const float*)d_in[2];
  const float* b1v  = (const float*)d_in[3];
  const float* W2   = (const float*)d_in[4];
  const float* P2   = (const float*)d_in[5];
  const float* b2   = (const float*)d_in[6];
  float* out = (float*)d_out;

  const size_t BITS_BYTES = (size_t)BSZ * T1 * 10 * sizeof(u32);  // 261,120 B

  if (ws_size >= BITS_BYTES) {
    u32* gbits = (u32*)d_ws;
    snn_l1<<<dim3(5, BSZ), 256, 0, stream>>>(data, W1, P1, b1v, gbits);
    snn_l2k<<<BSZ, 256, 0, stream>>>(gbits, W2, P2, b2, out);
  } else {
    snn_mono<<<BSZ, 256, 0, stream>>>(data, W1, P1, b1v, W2, P2, b2, out);
  }
}

// Round 2
// 1056.639 us; speedup vs baseline: 2.0768x; 1.0980x over previous
//
#include <hip/hip_runtime.h>

// Problem constants
#define BSZ  128
#define TT   50
#define CIN  2312
#define HID  300
#define NOUT 10
#define KS   5
#define T1   51          // (TT+5) - KS + 1
#define T2   52          // (T1+5) - KS + 1

#define NCHUNK 289       // CIN/8
#define K1_CH_STRIDE 3072  // floats per (ow,chunk) K1 block: 40*72=2880 + pad -> 12 KiB

typedef unsigned int u32;

// exp(-k^2/8) constants, k=1..4 (fp32)
#define EK1f 0.88249690258459546f
#define EK2f 0.60653065971263342f
#define EK3f 0.32465246735834974f
#define EK4f 0.13533528323661270f

#define AS1 __attribute__((address_space(1)))
#define AS3 __attribute__((address_space(3)))

// ===========================================================================
// PATH A: precompute gauss kernel K1 once (it is batch-independent!), in the
// exact LDS image layout [ow][chunk][k*8+isub][72] (stride 3072 floats =
// 12 KiB per chunk), then layer-1 stages it with async global_load_lds
// (3 dwordx4 per wave per chunk), double-buffered across the compute phase.
// ===========================================================================

__global__ __launch_bounds__(512) void snn_prep(
    const float* __restrict__ W1, const float* __restrict__ P1,
    float* __restrict__ K1)
{
  const int c   = blockIdx.x;          // 0..288
  const int ow  = blockIdx.y;          // 0..4
  const int tid = threadIdx.x;         // 512
  const int o    = tid & 63;
  const int isub = tid >> 6;
  const int bo = ow * 64 + o;
  float w = 0.f, p = 0.f;
  if (bo < HID) {
    const size_t gi = (size_t)bo * CIN + c * 8 + isub;
    w = W1[gi];
    p = P1[gi];
  }
  const float cc = p + 2.0f;                  // P + MAX_DELAY//2
  const float E0 = __expf(-0.125f * cc * cc);
  const float U  = __expf(0.25f * cc);
  const float u2 = U * U;
  const float e0 = E0;
  const float e1 = E0 * U * EK1f;
  const float e2 = E0 * u2 * EK2f;
  const float e3 = E0 * (u2 * U) * EK3f;
  const float e4 = E0 * (u2 * u2) * EK4f;
  const float inv = 1.0f / (((((e0 + e1) + e2) + e3) + e4) + 1e-7f);
  float* dst = K1 + ((size_t)(ow * NCHUNK) + c) * K1_CH_STRIDE + isub * 72 + o;
  dst[0]    = w * (e0 * inv);
  dst[576]  = w * (e1 * inv);
  dst[1152] = w * (e2 * inv);
  dst[1728] = w * (e3 * inv);
  dst[2304] = w * (e4 * inv);
}

// ---------------------------------------------------------------------------
// Layer-1 (PATH A): fp32 GEMM 64t(51 valid) x 64o over K = CIN*KS.
// B tiles streamed from K1 via global_load_lds, double-buffered (vmcnt(0)
// only at the consume point -> loads in flight across the compute phase).
// A staged as a 55-slot time window shared by all 5 taps (rows padded to 84
// floats -> conflict-free stage writes). Per-chunk fp32 partials promoted
// into fp64 accumulators. Then in-LDS fp64 LIF scan + ballot bit-pack.
// LDS: Bsf float[2][3072] at [0,6144); As float[8][84] at [6144,6816);
//      y1s double[51][64] overlays after the final sync.
// ---------------------------------------------------------------------------
__global__ __launch_bounds__(256) void snn_l1p(
    const float* __restrict__ data, const float* __restrict__ K1,
    const float* __restrict__ b1v, u32* __restrict__ gbits)
{
  __shared__ __align__(16) double dsm[3408];   // 27264 B
  float* Bsf = (float*)dsm;            // [2][3072]
  float* As  = (float*)dsm + 6144;     // [8][84]

  const int ow = blockIdx.x, b = blockIdx.y;
  const int tid = threadIdx.x;
  u32* bits = gbits + (size_t)b * 510;

  const int ty = tid >> 5;             // 0..7  -> rows 8ty..+7
  const int tx = tid & 31;             // 0..31 -> cols 2tx..+1
  const int r0 = ty << 3;
  const int c0 = tx << 1;

  const float* abase = data + (size_t)b * (TT * CIN);

  // stage-A per-thread constants (tid < 220 active)
  const int slot = tid >> 2;           // 0..54
  const int pair = tid & 3;            // 0..3 -> i-subs 2p,2p+1
  const int tp   = slot - 5;           // -5..49 (< TT always)

  // B-copy addressing: wave w copies 3 KiB per chunk (3 x dwordx4 wave-instr)
  const int w = tid >> 6;
  const float* k1lane = K1 + (size_t)(ow * NCHUNK) * K1_CH_STRIDE
                        + w * 768 + (tid & 63) * 4;   // per-lane global src
  float* bdst = Bsf + w * 768;         // wave-uniform LDS dst base

  double acc[8][2];
#pragma unroll
  for (int r = 0; r < 8; ++r) { acc[r][0] = 0.0; acc[r][1] = 0.0; }

  // ---- prologue: issue B chunk 0 -> buf 0; prefetch A chunk 0 ----
  float2 aA = make_float2(0.f, 0.f);
  if (tid < 220 && tp >= 0)
    aA = *(const float2*)(abase + (size_t)tp * CIN + 2 * pair);
  {
    const float* s0 = k1lane;
    __builtin_amdgcn_global_load_lds((const AS1 void*)(s0),       (AS3 void*)(bdst),       16, 0, 0);
    __builtin_amdgcn_global_load_lds((const AS1 void*)(s0 + 256), (AS3 void*)(bdst + 256), 16, 0, 0);
    __builtin_amdgcn_global_load_lds((const AS1 void*)(s0 + 512), (AS3 void*)(bdst + 512), 16, 0, 0);
  }

  int cur = 0;
  for (int c = 0; c < NCHUNK; ++c) {
    // ---- consume point: B(buf cur) must have landed; stage A from regs ----
    asm volatile("s_waitcnt vmcnt(0)" ::: "memory");
    if (tid < 220) {
      As[(2 * pair)     * 84 + slot] = aA.x;
      As[(2 * pair + 1) * 84 + slot] = aA.y;
    }
    __syncthreads();

    // ---- issue next chunk's B into buf^1 + next A into regs ----
    if (c + 1 < NCHUNK) {
      const float* s0 = k1lane + (size_t)(c + 1) * K1_CH_STRIDE;
      float* d0 = bdst + (cur ^ 1) * K1_CH_STRIDE;
      __builtin_amdgcn_global_load_lds((const AS1 void*)(s0),       (AS3 void*)(d0),       16, 0, 0);
      __builtin_amdgcn_global_load_lds((const AS1 void*)(s0 + 256), (AS3 void*)(d0 + 256), 16, 0, 0);
      __builtin_amdgcn_global_load_lds((const AS1 void*)(s0 + 512), (AS3 void*)(d0 + 512), 16, 0, 0);
      if (tid < 220 && tp >= 0)
        aA = *(const float2*)(abase + (size_t)tp * CIN + (c + 1) * 8 + 2 * pair);
    }

    // ---- compute: 8 i-steps x 5 taps x (8x2) micro-tile, fp32 ----
    const float* Bcur = Bsf + cur * K1_CH_STRIDE;
    float accf[8][2];
#pragma unroll
    for (int r = 0; r < 8; ++r) { accf[r][0] = 0.f; accf[r][1] = 0.f; }
#pragma unroll
    for (int kk = 0; kk < 8; ++kk) {
      const float* ap = &As[kk * 84 + r0];       // slots r0..r0+11 (16B-aligned)
      const float4 a0 = *(const float4*)(ap);
      const float4 a1 = *(const float4*)(ap + 4);
      const float4 a2 = *(const float4*)(ap + 8);
      float av[12];
      av[0] = a0.x; av[1] = a0.y; av[2]  = a0.z; av[3]  = a0.w;
      av[4] = a1.x; av[5] = a1.y; av[6]  = a1.z; av[7]  = a1.w;
      av[8] = a2.x; av[9] = a2.y; av[10] = a2.z; av[11] = a2.w;
      float bv[KS][2];
#pragma unroll
      for (int k = 0; k < KS; ++k) {
        const float2 bb = *(const float2*)&Bcur[(k * 8 + kk) * 72 + c0];
        bv[k][0] = bb.x; bv[k][1] = bb.y;
      }
#pragma unroll
      for (int k = 0; k < KS; ++k)
#pragma unroll
        for (int r = 0; r < 8; ++r) {
          accf[r][0] = fmaf(av[r + k], bv[k][0], accf[r][0]);
          accf[r][1] = fmaf(av[r + k], bv[k][1], accf[r][1]);
        }
    }
    // promote 40-term fp32 partial into fp64 accumulator
#pragma unroll
    for (int r = 0; r < 8; ++r) {
      acc[r][0] += (double)accf[r][0];
      acc[r][1] += (double)accf[r][1];
    }
    __syncthreads();
    cur ^= 1;
  }

  // ---- y1 tile -> LDS (overlays Bsf/As; fenced by loop-final sync) ----
  double* y1s = dsm;                   // [t][64], t<51
#pragma unroll
  for (int r = 0; r < 8; ++r) {
    const int t = r0 + r;
    if (t < T1) {
      y1s[t * 64 + c0]     = acc[r][0];
      y1s[t * 64 + c0 + 1] = acc[r][1];
    }
  }
  __syncthreads();

  // ---- fp64 LIF scan on wave 0 + ballot bit-pack ----
  if (tid < 64) {
    const int o = ow * 64 + tid;
    const bool valid = o < HID;
    const double bias = valid ? (double)b1v[o] : 0.0;
    double mem = 0.0;
    for (int t = 0; t < T1; ++t) {
      const double x = y1s[t * 64 + tid] + bias;
      const double reset = (mem > 1.0) ? 1.0 : 0.0;
      mem = __dsub_rn(__dadd_rn(__dmul_rn(0.9, mem), x), reset);
      const unsigned long long mk = __ballot(valid && (mem > 1.0));
      if (tid == 0)  bits[t * 10 + 2 * ow]     = (u32)mk;
      if (tid == 32) bits[t * 10 + 2 * ow + 1] = (u32)(mk >> 32);
    }
  }
}

// ===========================================================================
// PATH B fallback: round-1 layer-1 (gauss synthesized in-kernel) — used when
// workspace is too small for K1; also the body of the zero-ws mono kernel.
// ===========================================================================
__device__ __forceinline__ void layer1_tile_g(
    int b, int ow, int tid,
    const float* __restrict__ data, const float* __restrict__ W1,
    const float* __restrict__ P1, const float* __restrict__ b1v,
    double* __restrict__ dsm, u32* __restrict__ bits)
{
  float* Bsf = (float*)dsm;          // [k*8+isub][72]
  float* As  = (float*)dsm + 2880;   // [isub][80] slots

  const int ty = tid >> 5;
  const int tx = tid & 31;
  const int r0 = ty << 3;
  const int c0 = tx << 1;

  const float* abase = data + (size_t)b * (TT * CIN);

  const int slot = tid >> 2;
  const int pair = tid & 3;
  const int tp   = slot - 5;

  const int isub = tid & 7;
  const int oA = tid >> 3;
  const int oB = oA + 32;
  const int boA = ow * 64 + oA;
  const int boB = ow * 64 + oB;
  const bool vB = boB < HID;

  double acc[8][2];
#pragma unroll
  for (int r = 0; r < 8; ++r) { acc[r][0] = 0.0; acc[r][1] = 0.0; }

  float2 aA = make_float2(0.f, 0.f);
  float wA = 0.f, pA = 0.f, wB = 0.f, pB = 0.f;
  if (tid < 220 && tp >= 0)
    aA = *(const float2*)(abase + (size_t)tp * CIN + 2 * pair);
  wA = W1[(size_t)boA * CIN + isub];
  pA = P1[(size_t)boA * CIN + isub];
  if (vB) {
    wB = W1[(size_t)boB * CIN + isub];
    pB = P1[(size_t)boB * CIN + isub];
  }

  for (int i0 = 0; i0 < CIN; i0 += 8) {
    if (tid < 220) {
      As[(2 * pair) * 80 + slot]     = aA.x;
      As[(2 * pair + 1) * 80 + slot] = aA.y;
    }
    {
      const float c  = pA + 2.0f;
      const float E0 = __expf(-0.125f * c * c);
      const float U  = __expf(0.25f * c);
      const float u2 = U * U;
      const float e0 = E0;
      const float e1 = E0 * U * EK1f;
      const float e2 = E0 * u2 * EK2f;
      const float e3 = E0 * (u2 * U) * EK3f;
      const float e4 = E0 * (u2 * u2) * EK4f;
      const float inv = 1.0f / (((((e0 + e1) + e2) + e3) + e4) + 1e-7f);
      float* bp = Bsf + isub * 72 + oA;
      bp[0]    = wA * (e0 * inv);
      bp[576]  = wA * (e1 * inv);
      bp[1152] = wA * (e2 * inv);
      bp[1728] = wA * (e3 * inv);
      bp[2304] = wA * (e4 * inv);
    }
    {
      const float c  = pB + 2.0f;
      const float E0 = __expf(-0.125f * c * c);
      const float U  = __expf(0.25f * c);
      const float u2 = U * U;
      const float e0 = E0;
      const float e1 = E0 * U * EK1f;
      const float e2 = E0 * u2 * EK2f;
      const float e3 = E0 * (u2 * U) * EK3f;
      const float e4 = E0 * (u2 * u2) * EK4f;
      const float inv = 1.0f / (((((e0 + e1) + e2) + e3) + e4) + 1e-7f);
      float* bp = Bsf + isub * 72 + oB;
      bp[0]    = wB * (e0 * inv);
      bp[576]  = wB * (e1 * inv);
      bp[1152] = wB * (e2 * inv);
      bp[1728] = wB * (e3 * inv);
      bp[2304] = wB * (e4 * inv);
    }
    __syncthreads();

    const int i0n = i0 + 8;
    if (i0n < CIN) {
      if (tid < 220 && tp >= 0)
        aA = *(const float2*)(abase + (size_t)tp * CIN + i0n + 2 * pair);
      wA = W1[(size_t)boA * CIN + i0n + isub];
      pA = P1[(size_t)boA * CIN + i0n + isub];
      if (vB) {
        wB = W1[(size_t)boB * CIN + i0n + isub];
        pB = P1[(size_t)boB * CIN + i0n + isub];
      }
    }

    float accf[8][2];
#pragma unroll
    for (int r = 0; r < 8; ++r) { accf[r][0] = 0.f; accf[r][1] = 0.f; }
#pragma unroll
    for (int kk = 0; kk < 8; ++kk) {
      const float* ap = &As[kk * 80 + r0];
      const float4 a0 = *(const float4*)(ap);
      const float4 a1 = *(const float4*)(ap + 4);
      const float4 a2 = *(const float4*)(ap + 8);
      float av[12];
      av[0] = a0.x; av[1] = a0.y; av[2]  = a0.z; av[3]  = a0.w;
      av[4] = a1.x; av[5] = a1.y; av[6]  = a1.z; av[7]  = a1.w;
      av[8] = a2.x; av[9] = a2.y; av[10] = a2.z; av[11] = a2.w;
      float bv[KS][2];
#pragma unroll
      for (int k = 0; k < KS; ++k) {
        const float2 bb = *(const float2*)&Bsf[(k * 8 + kk) * 72 + c0];
        bv[k][0] = bb.x; bv[k][1] = bb.y;
      }
#pragma unroll
      for (int k = 0; k < KS; ++k)
#pragma unroll
        for (int r = 0; r < 8; ++r) {
          accf[r][0] = fmaf(av[r + k], bv[k][0], accf[r][0]);
          accf[r][1] = fmaf(av[r + k], bv[k][1], accf[r][1]);
        }
    }
#pragma unroll
    for (int r = 0; r < 8; ++r) {
      acc[r][0] += (double)accf[r][0];
      acc[r][1] += (double)accf[r][1];
    }
    __syncthreads();
  }

  double* y1s = dsm;
#pragma unroll
  for (int r = 0; r < 8; ++r) {
    const int t = r0 + r;
    if (t < T1) {
      y1s[t * 64 + c0]     = acc[r][0];
      y1s[t * 64 + c0 + 1] = acc[r][1];
    }
  }
  __syncthreads();

  if (tid < 64) {
    const int o = ow * 64 + tid;
    const bool valid = o < HID;
    const double bias = valid ? (double)b1v[o] : 0.0;
    double mem = 0.0;
    for (int t = 0; t < T1; ++t) {
      const double x = y1s[t * 64 + tid] + bias;
      const double reset = (mem > 1.0) ? 1.0 : 0.0;
      mem = __dsub_rn(__dadd_rn(__dmul_rn(0.9, mem), x), reset);
      const unsigned long long mk = __ballot(valid && (mem > 1.0));
      if (tid == 0)  bits[t * 10 + 2 * ow]     = (u32)mk;
      if (tid == 32) bits[t * 10 + 2 * ow + 1] = (u32)(mk >> 32);
    }
  }
  __syncthreads();
}

// ---------------------------------------------------------------------------
// Layer-2 conv + LIF2 (fp32), spike bits already in LDS at smem+15000.
// ---------------------------------------------------------------------------
__device__ __forceinline__ void layer2_lif2(
    int b, int tid, float* smem,
    const float* __restrict__ W2, const float* __restrict__ P2,
    const float* __restrict__ b2, float* __restrict__ out)
{
  float* K2s = smem;
  const u32* lbits = (const u32*)(smem + 15000);
  float* y2s = smem + 15510;

  for (int idx = tid; idx < NOUT * HID; idx += 256) {
    const int o = idx / HID, i = idx % HID;
    const float w = W2[idx], p = P2[idx];
    const float c = p + 2.0f;
    float e[KS], s = 0.f;
#pragma unroll
    for (int k = 0; k < KS; ++k) {
      const float d = ((float)k - c) * 0.5f;
      e[k] = __expf(-0.5f * d * d);
      s += e[k];
    }
    const float denom = s + 1e-7f;
#pragma unroll
    for (int k = 0; k < KS; ++k)
      K2s[(o * KS + k) * HID + i] = w * (e[k] / denom);
  }
  __syncthreads();                    // also fences lbits population

  for (int task = tid; task < T2 * NOUT; task += 256) {
    const int t2 = task / NOUT, o = task % NOUT;
    float acc = b2[o];
#pragma unroll
    for (int k = 0; k < KS; ++k) {
      const int tp = t2 + k - KS;
      if (tp < 0 || tp >= T1) continue;
      const float* kr = K2s + (o * KS + k) * HID;
      const u32* br = lbits + tp * 10;
      for (int i = 0; i < HID; ++i)
        acc = fmaf((float)((br[i >> 5] >> (i & 31)) & 1u), kr[i], acc);
    }
    y2s[task] = acc;
  }
  __syncthreads();

  if (tid < NOUT) {
    float mem = 0.f;
    for (int t = 0; t < T2; ++t) {
      const float x = y2s[t * NOUT + tid];
      const float reset = (mem > 1.0f) ? 1.0f : 0.0f;
      mem = __fsub_rn(__fadd_rn(__fmul_rn(0.9f, mem), x), reset);
      out[(size_t)t * (BSZ * NOUT) + b * NOUT + tid] = (mem > 1.0f) ? 1.0f : 0.0f;
      out[(size_t)T2 * BSZ * NOUT + (size_t)t * (BSZ * NOUT) + b * NOUT + tid] = mem;
    }
  }
}

// ---------------- split path (fallback B) ----------------------------------
__global__ __launch_bounds__(256) void snn_l1(
    const float* __restrict__ data, const float* __restrict__ W1,
    const float* __restrict__ P1, const float* __restrict__ b1v,
    u32* __restrict__ gbits)
{
  __shared__ double dsm[3264];       // 26112 B
  const int ow = blockIdx.x, b = blockIdx.y;
  layer1_tile_g(b, ow, threadIdx.x, data, W1, P1, b1v, dsm,
                gbits + (size_t)b * 510);
}

__global__ __launch_bounds__(256) void snn_l2k(
    const u32* __restrict__ gbits,
    const float* __restrict__ W2, const float* __restrict__ P2,
    const float* __restrict__ b2, float* __restrict__ out)
{
  __shared__ float smem[16030];      // 64120 B
  const int b = blockIdx.x, tid = threadIdx.x;
  u32* lbits = (u32*)(smem + 15000);
  for (int i = tid; i < 510; i += 256) lbits[i] = gbits[(size_t)b * 510 + i];
  layer2_lif2(b, tid, smem, W2, P2, b2, out);
}

// ---------------- zero-workspace fallback -----------------------------------
__global__ __launch_bounds__(256) void snn_mono(
    const float* __restrict__ data, const float* __restrict__ W1,
    const float* __restrict__ P1, const float* __restrict__ b1v,
    const float* __restrict__ W2, const float* __restrict__ P2,
    const float* __restrict__ b2, float* __restrict__ out)
{
  __shared__ double dsm[8015];       // 64120 B; layer1 uses [0,3264)
  const int b = blockIdx.x, tid = threadIdx.x;
  u32* lbits = (u32*)((float*)dsm + 15000);   // float-offset 15000 = byte 60000
  for (int ow = 0; ow < 5; ++ow)
    layer1_tile_g(b, ow, tid, data, W1, P1, b1v, dsm, lbits);
  layer2_lif2(b, tid, (float*)dsm, W2, P2, b2, out);
}

// ---------------- launcher --------------------------------------------------
extern "C" void kernel_launch(void* const* d_in, const int* in_sizes, int n_in,
                              void* d_out, int out_size, void* d_ws, size_t ws_size,
                              hipStream_t stream) {
  const float* data = (const float*)d_in[0];
  const float* W1   = (const float*)d_in[1];
  const float* P1   = (const float*)d_in[2];
  const float* b1v  = (const float*)d_in[3];
  const float* W2   = (const float*)d_in[4];
  const float* P2   = (const float*)d_in[5];
  const float* b2   = (const float*)d_in[6];
  float* out = (float*)d_out;

  const size_t BITS_BYTES = (size_t)BSZ * T1 * 10 * sizeof(u32);  // 261,120 B
  const size_t K1_OFF_FLOATS = 65536;                              // 256 KiB offset
  const size_t K1_FLOATS = (size_t)5 * NCHUNK * K1_CH_STRIDE;      // 4,439,040
  const size_t NEED_A = (K1_OFF_FLOATS + K1_FLOATS) * sizeof(float); // ~18.0 MB

  if (ws_size >= NEED_A) {
    u32*   gbits = (u32*)d_ws;
    float* K1    = (float*)d_ws + K1_OFF_FLOATS;
    snn_prep<<<dim3(NCHUNK, 5), 512, 0, stream>>>(W1, P1, K1);
    snn_l1p<<<dim3(5, BSZ), 256, 0, stream>>>(data, K1, b1v, gbits);
    snn_l2k<<<BSZ, 256, 0, stream>>>(gbits, W2, P2, b2, out);
  } else if (ws_size >= BITS_BYTES) {
    u32* gbits = (u32*)d_ws;
    snn_l1<<<dim3(5, BSZ), 256, 0, stream>>>(data, W1, P1, b1v, gbits);
    snn_l2k<<<BSZ, 256, 0, stream>>>(gbits, W2, P2, b2, out);
  } else {
    snn_mono<<<BSZ, 256, 0, stream>>>(data, W1, P1, b1v, W2, P2, b2, out);
  }
}

// Round 4
// 497.761 us; speedup vs baseline: 4.4087x; 2.1228x over previous
//
#include <hip/hip_runtime.h>

// Problem constants
#define BSZ  128
#define TT   50
#define CIN  2312
#define HID  300
#define NOUT 10
#define KS   5
#define T1   51          // (TT+5) - KS + 1
#define T2   52          // (T1+5) - KS + 1

#define NC32 73          // ceil(CIN/32) K-chunks of 32
#define KFRAG_U 20480    // u16 units per (ow,chunk): 5k * 4nt * 2h * 512

typedef unsigned int u32;
typedef unsigned short u16;
typedef __attribute__((ext_vector_type(8))) short s16x8;   // 8 bf16 (4 VGPRs)
typedef __attribute__((ext_vector_type(4))) float f32x4;   // MFMA C/D

// exp(-k^2/8) constants, k=1..4 (fp32)
#define EK1f 0.88249690258459546f
#define EK2f 0.60653065971263342f
#define EK3f 0.32465246735834974f
#define EK4f 0.13533528323661270f

static __device__ __forceinline__ u16 bfhi(float x) {
  u32 u = __float_as_uint(x);
  return (u16)((u + 0x7fffu + ((u >> 16) & 1u)) >> 16);   // RNE bf16
}
static __device__ __forceinline__ float bf2f(u16 h) {
  return __uint_as_float(((u32)h) << 16);
}

// ===========================================================================
// prep: synthesize gauss kernel once, split into bf16 hi/lo, in exact MFMA
// B-fragment order: [ow][chunk][k][nt][h][lane][8] (frag = 64 lanes x 16 B).
// B-frag layout for mfma_f32_16x16x32_bf16: lane l holds B[k-dim = (l>>4)*8+j]
// [n = l&15]; k-dim here = input channel i within the 32-chunk.
// ===========================================================================
__global__ __launch_bounds__(256) void snn_prepm(
    const float* __restrict__ W1, const float* __restrict__ P1,
    u16* __restrict__ K1bf)
{
  const int c  = blockIdx.x;          // 0..72
  const int ow = blockIdx.y;          // 0..4
  const int tid = threadIdx.x;
  const int nt = tid >> 6, ll = tid & 63;
  const int g = ll >> 4, lr = ll & 15;
  const int o  = ow * 64 + nt * 16 + lr;
  const int ib = c * 32 + g * 8;

  s16x8 hv[5], lv[5];
#pragma unroll
  for (int k = 0; k < 5; ++k)
#pragma unroll
    for (int j = 0; j < 8; ++j) { hv[k][j] = 0; lv[k][j] = 0; }

  if (o < HID) {
    const float* wrow = W1 + (size_t)o * CIN;
    const float* prow = P1 + (size_t)o * CIN;
#pragma unroll
    for (int j = 0; j < 8; ++j) {
      const int i = ib + j;
      if (i < CIN) {
        const float w1 = wrow[i], p1 = prow[i];
        const float cc = p1 + 2.0f;
        const float E0 = __expf(-0.125f * cc * cc);
        const float U  = __expf(0.25f * cc);
        const float u2 = U * U;
        const float e0 = E0;
        const float e1 = E0 * U * EK1f;
        const float e2 = E0 * u2 * EK2f;
        const float e3 = E0 * (u2 * U) * EK3f;
        const float e4 = E0 * (u2 * u2) * EK4f;
        const float inv = 1.0f / (((((e0 + e1) + e2) + e3) + e4) + 1e-7f);
        const float vk[5] = { w1 * (e0 * inv), w1 * (e1 * inv),
                              w1 * (e2 * inv), w1 * (e3 * inv),
                              w1 * (e4 * inv) };
#pragma unroll
        for (int k = 0; k < 5; ++k) {
          const u16 h = bfhi(vk[k]);
          const u16 lo = bfhi(vk[k] - bf2f(h));
          hv[k][j] = (short)h; lv[k][j] = (short)lo;
        }
      }
    }
  }
  u16* base = K1bf + ((size_t)ow * NC32 + c) * KFRAG_U + nt * 1024 + ll * 8;
#pragma unroll
  for (int k = 0; k < 5; ++k) {
    *(s16x8*)(base + k * 4096)       = hv[k];
    *(s16x8*)(base + k * 4096 + 512) = lv[k];
  }
}

// ===========================================================================
// Layer-1 MFMA path. Per block (ow,b): C[64 t][64 o] over K = CIN*KS via
// mfma_f32_16x16x32_bf16, 3-term bf16 split (ah*bh + al*bh + ah*bl).
// 4 waves; wave w owns rows 16w..16w+15, all 64 cols (4 n-tiles).
// A (time window, 68 slots x 32 i, hi/lo bf16) staged in LDS per chunk,
// rows padded to 40 units (80 B) -> bank-balanced b128 reads.
// B fragments read directly global->VGPR from prep's layout (L2-served).
// Per-chunk fp32 MFMA partials promoted into fp64 accumulators.
// XCD-aware b-major swizzle: consecutive blocks on an XCD share batch rows.
// LDS: A hi [0,2720) u16, A lo [2720,5440); y1s double[51][64] overlays.
// ===========================================================================
__global__ __launch_bounds__(256) void snn_l1m(
    const float* __restrict__ data, const u16* __restrict__ K1bf,
    const float* __restrict__ b1v, u32* __restrict__ gbits)
{
  __shared__ double dsm[3264];         // 26112 B
  u16* A16 = (u16*)dsm;

  const int tid = threadIdx.x;
  const int bid = blockIdx.x;
  const int rank = (bid & 7) * 80 + (bid >> 3);   // bijective, 640 = 8*80
  const int ow = rank % 5, b = rank / 5;          // b-major per XCD

  const int w  = tid >> 6, l = tid & 63;
  const int lr = l & 15, lg = l >> 4;
  const int rowA = (16 * w + lr) * 40 + lg * 8;   // A-frag base (u16 units)

  const float* abase = data + (size_t)b * (TT * CIN);
  const u16* kbase = K1bf + (size_t)ow * NC32 * KFRAG_U + l * 8;

  // A staging: thread -> (slot s1 = tid>>2 in 0..63, i-group j4 = tid&3)
  const int s1 = tid >> 2;
  const int j4 = tid & 3;
  const int tp = s1 - 5;
  const bool av = (tp >= 0) && (tp < TT);
  const float* aptr = abase + (size_t)(av ? tp : 0) * CIN + j4 * 8;

  // zero A rows 64..67 (read by tap overhang into discarded C rows)
  if (tid < 20) {
    s16x8 z;
#pragma unroll
    for (int j = 0; j < 8; ++j) z[j] = 0;
    *(s16x8*)(A16 + 2560 + tid * 8) = z;
    *(s16x8*)(A16 + 2720 + 2560 + tid * 8) = z;
  }

  f32x4 accf[4];
  double accd[4][4];
#pragma unroll
  for (int nt = 0; nt < 4; ++nt)
#pragma unroll
    for (int q = 0; q < 4; ++q) { accf[nt][q] = 0.f; accd[nt][q] = 0.0; }

  // prefetch A chunk 0 (chunk 0 is always i-valid)
  float4 ra0, ra1;
  {
    ra0 = av ? *(const float4*)(aptr)     : make_float4(0.f, 0.f, 0.f, 0.f);
    ra1 = av ? *(const float4*)(aptr + 4) : make_float4(0.f, 0.f, 0.f, 0.f);
  }

  for (int c = 0; c < NC32; ++c) {
    __syncthreads();
    // ---- stage A(c): fp32 regs -> bf16 hi/lo LDS ----
    {
      const float f[8] = { ra0.x, ra0.y, ra0.z, ra0.w,
                           ra1.x, ra1.y, ra1.z, ra1.w };
      s16x8 hv, lv;
#pragma unroll
      for (int j = 0; j < 8; ++j) {
        const u16 h = bfhi(f[j]);
        hv[j] = (short)h;
        lv[j] = (short)bfhi(f[j] - bf2f(h));
      }
      *(s16x8*)(A16 + s1 * 40 + j4 * 8) = hv;
      *(s16x8*)(A16 + 2720 + s1 * 40 + j4 * 8) = lv;
    }
    __syncthreads();

    // ---- prefetch next A chunk (latency hidden under MFMAs) ----
    if (c + 1 < NC32) {
      const int cn = c + 1;
      const bool iv = av && ((cn < 72) || (j4 == 0));   // chunk 72: only i<2312
      const float* p = aptr + cn * 32;
      ra0 = iv ? *(const float4*)(p)     : make_float4(0.f, 0.f, 0.f, 0.f);
      ra1 = iv ? *(const float4*)(p + 4) : make_float4(0.f, 0.f, 0.f, 0.f);
    }

    // ---- 5 taps x 4 n-tiles x 3 split-terms of MFMA ----
    const u16* cb = kbase + (size_t)c * KFRAG_U;
#pragma unroll
    for (int k = 0; k < 5; ++k) {
      const u16* tb = cb + k * 4096;
      s16x8 bh[4], bl[4];
#pragma unroll
      for (int nt = 0; nt < 4; ++nt) {
        bh[nt] = *(const s16x8*)(tb + nt * 1024);
        bl[nt] = *(const s16x8*)(tb + nt * 1024 + 512);
      }
      const s16x8 ah = *(const s16x8*)(A16 + rowA + k * 40);
      const s16x8 al = *(const s16x8*)(A16 + 2720 + rowA + k * 40);
#pragma unroll
      for (int nt = 0; nt < 4; ++nt) {
        accf[nt] = __builtin_amdgcn_mfma_f32_16x16x32_bf16(ah, bh[nt], accf[nt], 0, 0, 0);
        accf[nt] = __builtin_amdgcn_mfma_f32_16x16x32_bf16(al, bh[nt], accf[nt], 0, 0, 0);
        accf[nt] = __builtin_amdgcn_mfma_f32_16x16x32_bf16(ah, bl[nt], accf[nt], 0, 0, 0);
      }
    }
    // ---- promote chunk partial into fp64 ----
#pragma unroll
    for (int nt = 0; nt < 4; ++nt)
#pragma unroll
      for (int q = 0; q < 4; ++q) {
        accd[nt][q] += (double)accf[nt][q];
        accf[nt][q] = 0.f;
      }
  }

  __syncthreads();
  // ---- y1 tile -> LDS (overlays A; fenced above) ----
  // C/D layout (m89-verified): col = lane&15, row = (lane>>4)*4 + reg
  double* y1s = dsm;
#pragma unroll
  for (int nt = 0; nt < 4; ++nt)
#pragma unroll
    for (int q = 0; q < 4; ++q) {
      const int t = 16 * w + lg * 4 + q;
      if (t < T1) y1s[t * 64 + nt * 16 + lr] = accd[nt][q];
    }
  __syncthreads();

  // ---- fp64 LIF scan on wave 0 + ballot bit-pack ----
  if (tid < 64) {
    const int o = ow * 64 + tid;
    const bool valid = o < HID;
    const double bias = valid ? (double)b1v[o] : 0.0;
    u32* bits = gbits + (size_t)b * 510;
    double mem = 0.0;
    for (int t = 0; t < T1; ++t) {
      const double x = y1s[t * 64 + tid] + bias;
      const double reset = (mem > 1.0) ? 1.0 : 0.0;
      mem = __dsub_rn(__dadd_rn(__dmul_rn(0.9, mem), x), reset);
      const unsigned long long mk = __ballot(valid && (mem > 1.0));
      if (tid == 0)  bits[t * 10 + 2 * ow]     = (u32)mk;
      if (tid == 32) bits[t * 10 + 2 * ow + 1] = (u32)(mk >> 32);
    }
  }
}

// ===========================================================================
// Fallback layer-1 (fp32, gauss in-kernel) — round-1/2 proven path.
// ===========================================================================
__device__ __forceinline__ void layer1_tile_g(
    int b, int ow, int tid,
    const float* __restrict__ data, const float* __restrict__ W1,
    const float* __restrict__ P1, const float* __restrict__ b1v,
    double* __restrict__ dsm, u32* __restrict__ bits)
{
  float* Bsf = (float*)dsm;
  float* As  = (float*)dsm + 2880;

  const int ty = tid >> 5;
  const int tx = tid & 31;
  const int r0 = ty << 3;
  const int c0 = tx << 1;

  const float* abase = data + (size_t)b * (TT * CIN);

  const int slot = tid >> 2;
  const int pair = tid & 3;
  const int tp   = slot - 5;

  const int isub = tid & 7;
  const int oA = tid >> 3;
  const int oB = oA + 32;
  const int boA = ow * 64 + oA;
  const int boB = ow * 64 + oB;
  const bool vB = boB < HID;

  double acc[8][2];
#pragma unroll
  for (int r = 0; r < 8; ++r) { acc[r][0] = 0.0; acc[r][1] = 0.0; }

  float2 aA = make_float2(0.f, 0.f);
  float wA = 0.f, pA = 0.f, wB = 0.f, pB = 0.f;
  if (tid < 220 && tp >= 0)
    aA = *(const float2*)(abase + (size_t)tp * CIN + 2 * pair);
  wA = W1[(size_t)boA * CIN + isub];
  pA = P1[(size_t)boA * CIN + isub];
  if (vB) {
    wB = W1[(size_t)boB * CIN + isub];
    pB = P1[(size_t)boB * CIN + isub];
  }

  for (int i0 = 0; i0 < CIN; i0 += 8) {
    if (tid < 220) {
      As[(2 * pair) * 80 + slot]     = aA.x;
      As[(2 * pair + 1) * 80 + slot] = aA.y;
    }
    {
      const float c  = pA + 2.0f;
      const float E0 = __expf(-0.125f * c * c);
      const float U  = __expf(0.25f * c);
      const float u2 = U * U;
      const float e0 = E0;
      const float e1 = E0 * U * EK1f;
      const float e2 = E0 * u2 * EK2f;
      const float e3 = E0 * (u2 * U) * EK3f;
      const float e4 = E0 * (u2 * u2) * EK4f;
      const float inv = 1.0f / (((((e0 + e1) + e2) + e3) + e4) + 1e-7f);
      float* bp = Bsf + isub * 72 + oA;
      bp[0]    = wA * (e0 * inv);
      bp[576]  = wA * (e1 * inv);
      bp[1152] = wA * (e2 * inv);
      bp[1728] = wA * (e3 * inv);
      bp[2304] = wA * (e4 * inv);
    }
    {
      const float c  = pB + 2.0f;
      const float E0 = __expf(-0.125f * c * c);
      const float U  = __expf(0.25f * c);
      const float u2 = U * U;
      const float e0 = E0;
      const float e1 = E0 * U * EK1f;
      const float e2 = E0 * u2 * EK2f;
      const float e3 = E0 * (u2 * U) * EK3f;
      const float e4 = E0 * (u2 * u2) * EK4f;
      const float inv = 1.0f / (((((e0 + e1) + e2) + e3) + e4) + 1e-7f);
      float* bp = Bsf + isub * 72 + oB;
      bp[0]    = wB * (e0 * inv);
      bp[576]  = wB * (e1 * inv);
      bp[1152] = wB * (e2 * inv);
      bp[1728] = wB * (e3 * inv);
      bp[2304] = wB * (e4 * inv);
    }
    __syncthreads();

    const int i0n = i0 + 8;
    if (i0n < CIN) {
      if (tid < 220 && tp >= 0)
        aA = *(const float2*)(abase + (size_t)tp * CIN + i0n + 2 * pair);
      wA = W1[(size_t)boA * CIN + i0n + isub];
      pA = P1[(size_t)boA * CIN + i0n + isub];
      if (vB) {
        wB = W1[(size_t)boB * CIN + i0n + isub];
        pB = P1[(size_t)boB * CIN + i0n + isub];
      }
    }

    float accf[8][2];
#pragma unroll
    for (int r = 0; r < 8; ++r) { accf[r][0] = 0.f; accf[r][1] = 0.f; }
#pragma unroll
    for (int kk = 0; kk < 8; ++kk) {
      const float* ap = &As[kk * 80 + r0];
      const float4 a0 = *(const float4*)(ap);
      const float4 a1 = *(const float4*)(ap + 4);
      const float4 a2 = *(const float4*)(ap + 8);
      float av[12];
      av[0] = a0.x; av[1] = a0.y; av[2]  = a0.z; av[3]  = a0.w;
      av[4] = a1.x; av[5] = a1.y; av[6]  = a1.z; av[7]  = a1.w;
      av[8] = a2.x; av[9] = a2.y; av[10] = a2.z; av[11] = a2.w;
      float bv[KS][2];
#pragma unroll
      for (int k = 0; k < KS; ++k) {
        const float2 bb = *(const float2*)&Bsf[(k * 8 + kk) * 72 + c0];
        bv[k][0] = bb.x; bv[k][1] = bb.y;
      }
#pragma unroll
      for (int k = 0; k < KS; ++k)
#pragma unroll
        for (int r = 0; r < 8; ++r) {
          accf[r][0] = fmaf(av[r + k], bv[k][0], accf[r][0]);
          accf[r][1] = fmaf(av[r + k], bv[k][1], accf[r][1]);
        }
    }
#pragma unroll
    for (int r = 0; r < 8; ++r) {
      acc[r][0] += (double)accf[r][0];
      acc[r][1] += (double)accf[r][1];
    }
    __syncthreads();
  }

  double* y1s = dsm;
#pragma unroll
  for (int r = 0; r < 8; ++r) {
    const int t = r0 + r;
    if (t < T1) {
      y1s[t * 64 + c0]     = acc[r][0];
      y1s[t * 64 + c0 + 1] = acc[r][1];
    }
  }
  __syncthreads();

  if (tid < 64) {
    const int o = ow * 64 + tid;
    const bool valid = o < HID;
    const double bias = valid ? (double)b1v[o] : 0.0;
    double mem = 0.0;
    for (int t = 0; t < T1; ++t) {
      const double x = y1s[t * 64 + tid] + bias;
      const double reset = (mem > 1.0) ? 1.0 : 0.0;
      mem = __dsub_rn(__dadd_rn(__dmul_rn(0.9, mem), x), reset);
      const unsigned long long mk = __ballot(valid && (mem > 1.0));
      if (tid == 0)  bits[t * 10 + 2 * ow]     = (u32)mk;
      if (tid == 32) bits[t * 10 + 2 * ow + 1] = (u32)(mk >> 32);
    }
  }
  __syncthreads();
}

// ---------------------------------------------------------------------------
// Layer-2 conv + LIF2 (fp32), spike bits already in LDS at smem+15000.
// ---------------------------------------------------------------------------
__device__ __forceinline__ void layer2_lif2(
    int b, int tid, float* smem,
    const float* __restrict__ W2, const float* __restrict__ P2,
    const float* __restrict__ b2, float* __restrict__ out)
{
  float* K2s = smem;
  const u32* lbits = (const u32*)(smem + 15000);
  float* y2s = smem + 15510;

  for (int idx = tid; idx < NOUT * HID; idx += 256) {
    const int o = idx / HID, i = idx % HID;
    const float w = W2[idx], p = P2[idx];
    const float c = p + 2.0f;
    float e[KS], s = 0.f;
#pragma unroll
    for (int k = 0; k < KS; ++k) {
      const float d = ((float)k - c) * 0.5f;
      e[k] = __expf(-0.5f * d * d);
      s += e[k];
    }
    const float denom = s + 1e-7f;
#pragma unroll
    for (int k = 0; k < KS; ++k)
      K2s[(o * KS + k) * HID + i] = w * (e[k] / denom);
  }
  __syncthreads();                    // also fences lbits population

  for (int task = tid; task < T2 * NOUT; task += 256) {
    const int t2 = task / NOUT, o = task % NOUT;
    float acc = b2[o];
#pragma unroll
    for (int k = 0; k < KS; ++k) {
      const int tp = t2 + k - KS;
      if (tp < 0 || tp >= T1) continue;
      const float* kr = K2s + (o * KS + k) * HID;
      const u32* br = lbits + tp * 10;
      for (int i = 0; i < HID; ++i)
        acc = fmaf((float)((br[i >> 5] >> (i & 31)) & 1u), kr[i], acc);
    }
    y2s[task] = acc;
  }
  __syncthreads();

  if (tid < NOUT) {
    float mem = 0.f;
    for (int t = 0; t < T2; ++t) {
      const float x = y2s[t * NOUT + tid];
      const float reset = (mem > 1.0f) ? 1.0f : 0.0f;
      mem = __fsub_rn(__fadd_rn(__fmul_rn(0.9f, mem), x), reset);
      out[(size_t)t * (BSZ * NOUT) + b * NOUT + tid] = (mem > 1.0f) ? 1.0f : 0.0f;
      out[(size_t)T2 * BSZ * NOUT + (size_t)t * (BSZ * NOUT) + b * NOUT + tid] = mem;
    }
  }
}

// ---------------- split-path kernels ----------------------------------------
__global__ __launch_bounds__(256) void snn_l1(
    const float* __restrict__ data, const float* __restrict__ W1,
    const float* __restrict__ P1, const float* __restrict__ b1v,
    u32* __restrict__ gbits)
{
  __shared__ double dsm[3264];
  const int ow = blockIdx.x, b = blockIdx.y;
  layer1_tile_g(b, ow, threadIdx.x, data, W1, P1, b1v, dsm,
                gbits + (size_t)b * 510);
}

__global__ __launch_bounds__(256) void snn_l2k(
    const u32* __restrict__ gbits,
    const float* __restrict__ W2, const float* __restrict__ P2,
    const float* __restrict__ b2, float* __restrict__ out)
{
  __shared__ float smem[16030];
  const int b = blockIdx.x, tid = threadIdx.x;
  u32* lbits = (u32*)(smem + 15000);
  for (int i = tid; i < 510; i += 256) lbits[i] = gbits[(size_t)b * 510 + i];
  layer2_lif2(b, tid, smem, W2, P2, b2, out);
}

// ---------------- zero-workspace fallback -----------------------------------
__global__ __launch_bounds__(256) void snn_mono(
    const float* __restrict__ data, const float* __restrict__ W1,
    const float* __restrict__ P1, const float* __restrict__ b1v,
    const float* __restrict__ W2, const float* __restrict__ P2,
    const float* __restrict__ b2, float* __restrict__ out)
{
  __shared__ double dsm[8015];
  const int b = blockIdx.x, tid = threadIdx.x;
  u32* lbits = (u32*)((float*)dsm + 15000);
  for (int ow = 0; ow < 5; ++ow)
    layer1_tile_g(b, ow, tid, data, W1, P1, b1v, dsm, lbits);
  layer2_lif2(b, tid, (float*)dsm, W2, P2, b2, out);
}

// ---------------- launcher --------------------------------------------------
extern "C" void kernel_launch(void* const* d_in, const int* in_sizes, int n_in,
                              void* d_out, int out_size, void* d_ws, size_t ws_size,
                              hipStream_t stream) {
  const float* data = (const float*)d_in[0];
  const float* W1   = (const float*)d_in[1];
  const float* P1   = (const float*)d_in[2];
  const float* b1v  = (const float*)d_in[3];
  const float* W2   = (const float*)d_in[4];
  const float* P2   = (const float*)d_in[5];
  const float* b2   = (const float*)d_in[6];
  float* out = (float*)d_out;

  const size_t BITS_BYTES = (size_t)BSZ * T1 * 10 * sizeof(u32);   // 261,120 B
  const size_t K1_OFF = 262144;                                     // 256 KiB
  const size_t K1BF_BYTES = (size_t)5 * NC32 * KFRAG_U * 2;         // 14,950,400
  const size_t NEED_M = K1_OFF + K1BF_BYTES;                        // ~15.2 MB

  if (ws_size >= NEED_M) {
    u32* gbits = (u32*)d_ws;
    u16* K1bf  = (u16*)((char*)d_ws + K1_OFF);
    snn_prepm<<<dim3(NC32, 5), 256, 0, stream>>>(W1, P1, K1bf);
    snn_l1m<<<640, 256, 0, stream>>>(data, K1bf, b1v, gbits);
    snn_l2k<<<BSZ, 256, 0, stream>>>(gbits, W2, P2, b2, out);
  } else if (ws_size >= BITS_BYTES) {
    u32* gbits = (u32*)d_ws;
    snn_l1<<<dim3(5, BSZ), 256, 0, stream>>>(data, W1, P1, b1v, gbits);
    snn_l2k<<<BSZ, 256, 0, stream>>>(gbits, W2, P2, b2, out);
  } else {
    snn_mono<<<BSZ, 256, 0, stream>>>(data, W1, P1, b1v, W2, P2, b2, out);
  }
}

// Round 5
// 401.415 us; speedup vs baseline: 5.4668x; 1.2400x over previous
//
#include <hip/hip_runtime.h>

// Problem constants
#define BSZ  128
#define TT   50
#define CIN  2312
#define HID  300
#define NOUT 10
#define KS   5
#define T1   51          // (TT+5) - KS + 1
#define T2   52          // (T1+5) - KS + 1

#define NC32 73          // ceil(CIN/32) K-chunks of 32
#define KFRAG_U 20480    // u16 units per (ow,chunk): 5k * 4nt * 2h * 512

typedef unsigned int u32;
typedef unsigned short u16;
typedef __attribute__((ext_vector_type(8))) short s16x8;   // 8 bf16 (4 VGPRs)
typedef __attribute__((ext_vector_type(4))) float f32x4;   // MFMA C/D

// exp(-k^2/8) constants, k=1..4 (fp32)
#define EK1f 0.88249690258459546f
#define EK2f 0.60653065971263342f
#define EK3f 0.32465246735834974f
#define EK4f 0.13533528323661270f

static __device__ __forceinline__ u16 bfhi(float x) {
  u32 u = __float_as_uint(x);
  return (u16)((u + 0x7fffu + ((u >> 16) & 1u)) >> 16);   // RNE bf16
}
static __device__ __forceinline__ float bf2f(u16 h) {
  return __uint_as_float(((u32)h) << 16);
}

// ===========================================================================
// prep: synthesize gauss kernel once, split into bf16 hi/lo, in exact MFMA
// B-fragment order: [ow][chunk][k][nt][h][lane][8] (frag = 64 lanes x 16 B).
// B-frag layout for mfma_f32_16x16x32_bf16: lane l holds B[k-dim = (l>>4)*8+j]
// [n = l&15]; k-dim here = input channel i within the 32-chunk.
// ===========================================================================
__global__ __launch_bounds__(256) void snn_prepm(
    const float* __restrict__ W1, const float* __restrict__ P1,
    u16* __restrict__ K1bf)
{
  const int c  = blockIdx.x;          // 0..72
  const int ow = blockIdx.y;          // 0..4
  const int tid = threadIdx.x;
  const int nt = tid >> 6, ll = tid & 63;
  const int g = ll >> 4, lr = ll & 15;
  const int o  = ow * 64 + nt * 16 + lr;
  const int ib = c * 32 + g * 8;

  s16x8 hv[5], lv[5];
#pragma unroll
  for (int k = 0; k < 5; ++k)
#pragma unroll
    for (int j = 0; j < 8; ++j) { hv[k][j] = 0; lv[k][j] = 0; }

  if (o < HID) {
    const float* wrow = W1 + (size_t)o * CIN;
    const float* prow = P1 + (size_t)o * CIN;
#pragma unroll
    for (int j = 0; j < 8; ++j) {
      const int i = ib + j;
      if (i < CIN) {
        const float w1 = wrow[i], p1 = prow[i];
        const float cc = p1 + 2.0f;
        const float E0 = __expf(-0.125f * cc * cc);
        const float U  = __expf(0.25f * cc);
        const float u2 = U * U;
        const float e0 = E0;
        const float e1 = E0 * U * EK1f;
        const float e2 = E0 * u2 * EK2f;
        const float e3 = E0 * (u2 * U) * EK3f;
        const float e4 = E0 * (u2 * u2) * EK4f;
        const float inv = 1.0f / (((((e0 + e1) + e2) + e3) + e4) + 1e-7f);
        const float vk[5] = { w1 * (e0 * inv), w1 * (e1 * inv),
                              w1 * (e2 * inv), w1 * (e3 * inv),
                              w1 * (e4 * inv) };
#pragma unroll
        for (int k = 0; k < 5; ++k) {
          const u16 h = bfhi(vk[k]);
          const u16 lo = bfhi(vk[k] - bf2f(h));
          hv[k][j] = (short)h; lv[k][j] = (short)lo;
        }
      }
    }
  }
  u16* base = K1bf + ((size_t)ow * NC32 + c) * KFRAG_U + nt * 1024 + ll * 8;
#pragma unroll
  for (int k = 0; k < 5; ++k) {
    *(s16x8*)(base + k * 4096)       = hv[k];
    *(s16x8*)(base + k * 4096 + 512) = lv[k];
  }
}

// ===========================================================================
// Layer-1 MFMA path, v2.
// Per block (ow,b): C[64 t][64 o] over K = CIN*KS, mfma_f32_16x16x32_bf16,
// 3-term bf16 split (ah*bh + al*bh + ah*bl), per-chunk fp64 promotion.
// 4 waves in a 2x2 grid: wave (wr,wc) owns rows 32wr..+31, cols 32wc..+31.
// B: 20 frags/wave/chunk held in REGISTERS, rolling per-tap reload (each
//    tap's 4 frags re-loaded for chunk c+1 right after their last use ->
//    ~400 cyc of MFMA to hide the L2 latency; no LDS for B).
// A: time-window (64 slots + 4 pad) x 32 i, bf16 hi/lo, DOUBLE-buffered in
//    LDS (2 x 5440 u16) -> one barrier per chunk.
// XCD swizzle: rank=(bid&7)*80+(bid>>3); ow=rank>>7, b=rank&127 -> each XCD
//    sees 1-2 ow values (K1bf slice <= 5.8 MB ~ L2) and contiguous b.
// LDS: A buffers [0, 21760) u16; y1s double[51][64] overlays after loop.
// ===========================================================================
__global__ __launch_bounds__(256, 2) void snn_l1m(
    const float* __restrict__ data, const u16* __restrict__ K1bf,
    const float* __restrict__ b1v, u32* __restrict__ gbits)
{
  __shared__ double dsm[3264];         // 26112 B
  u16* A16 = (u16*)dsm;

  const int tid = threadIdx.x;
  const int bid = blockIdx.x;
  const int rnk = (bid & 7) * 80 + (bid >> 3);   // bijective, 640 = 8*80
  const int ow = rnk >> 7;                        // 0..4 (ow-major per XCD)
  const int b  = rnk & 127;

  const int w  = tid >> 6, l = tid & 63;
  const int lr = l & 15, lg = l >> 4;
  const int wr = w >> 1, wc = w & 1;
  const int abase_u = (32 * wr + lr) * 40 + lg * 8;   // A-frag base (u16)

  const float* dbase = data + (size_t)b * (TT * CIN);
  const u16* kb = K1bf + (size_t)ow * NC32 * KFRAG_U + l * 8;
  const int ntg0 = wc * 2, ntg1 = wc * 2 + 1;

  // A staging thread mapping: slot s1 (0..63), i-group j4 (0..3)
  const int s1 = tid >> 2;
  const int j4 = tid & 3;
  const int tp = s1 - 5;
  const bool avld = (tp >= 0) && (tp < TT);
  const float* aptr = dbase + (size_t)(avld ? tp : 0) * CIN + j4 * 8;

#define LDB(c_, k_, ntg_, h_) \
  (*(const s16x8*)(kb + (size_t)(c_) * KFRAG_U + (k_) * 4096 + (ntg_) * 1024 + (h_) * 512))

  // ---- B frag registers: 20 per wave ----
  s16x8 bh[5][2], bl[5][2];
#pragma unroll
  for (int k = 0; k < 5; ++k) {
    bh[k][0] = LDB(0, k, ntg0, 0); bh[k][1] = LDB(0, k, ntg1, 0);
    bl[k][0] = LDB(0, k, ntg0, 1); bl[k][1] = LDB(0, k, ntg1, 1);
  }

  // ---- A prefetch regs ----
  float4 ra0, ra1;
  {
    ra0 = avld ? *(const float4*)(aptr)     : make_float4(0.f, 0.f, 0.f, 0.f);
    ra1 = avld ? *(const float4*)(aptr + 4) : make_float4(0.f, 0.f, 0.f, 0.f);
  }

  // zero pad rows 64..67 (tap overhang) in BOTH buffers, hi+lo:
  // 4 regions of 160 u16 at r*2720 + 2560, r=0..3
  if (tid < 80) {
    s16x8 z;
#pragma unroll
    for (int j = 0; j < 8; ++j) z[j] = 0;
    const int r = tid / 20, off = (tid % 20) * 8;
    *(s16x8*)(A16 + r * 2720 + 2560 + off) = z;
  }

  // stage chunk 0 into buffer 0
  {
    const float f[8] = { ra0.x, ra0.y, ra0.z, ra0.w,
                         ra1.x, ra1.y, ra1.z, ra1.w };
    s16x8 hv, lv;
#pragma unroll
    for (int j = 0; j < 8; ++j) {
      const u16 h = bfhi(f[j]);
      hv[j] = (short)h;
      lv[j] = (short)bfhi(f[j] - bf2f(h));
    }
    *(s16x8*)(A16 + s1 * 40 + j4 * 8) = hv;
    *(s16x8*)(A16 + 2720 + s1 * 40 + j4 * 8) = lv;
  }
  // reload A regs <- chunk 1
  {
    const bool iv = avld;                 // chunk 1 < 72: all i valid
    const float* p = aptr + 32;
    ra0 = iv ? *(const float4*)(p)     : make_float4(0.f, 0.f, 0.f, 0.f);
    ra1 = iv ? *(const float4*)(p + 4) : make_float4(0.f, 0.f, 0.f, 0.f);
  }
  __syncthreads();

  f32x4 accf[2][2];
  double accd[2][2][4];
#pragma unroll
  for (int m = 0; m < 2; ++m)
#pragma unroll
    for (int n = 0; n < 2; ++n)
#pragma unroll
      for (int q = 0; q < 4; ++q) { accf[m][n][q] = 0.f; accd[m][n][q] = 0.0; }

  int p = 0;
  for (int c = 0; c < NC32; ++c) {
    u16* bufC = A16 + p * 2720 * 2;     // reads chunk c
    u16* bufN = A16 + (p ^ 1) * 2720 * 2;

    // ---- stage A(c+1) into the other buffer; reload A regs <- c+2 ----
    if (c + 1 < NC32) {
      const float f[8] = { ra0.x, ra0.y, ra0.z, ra0.w,
                           ra1.x, ra1.y, ra1.z, ra1.w };
      s16x8 hv, lv;
#pragma unroll
      for (int j = 0; j < 8; ++j) {
        const u16 h = bfhi(f[j]);
        hv[j] = (short)h;
        lv[j] = (short)bfhi(f[j] - bf2f(h));
      }
      *(s16x8*)(bufN + s1 * 40 + j4 * 8) = hv;
      *(s16x8*)(bufN + 2720 + s1 * 40 + j4 * 8) = lv;

      const int cn = (c + 2 < NC32) ? c + 2 : NC32 - 1;
      const bool iv = avld && ((cn < 72) || (j4 == 0));
      const float* pp = aptr + cn * 32;
      ra0 = iv ? *(const float4*)(pp)     : make_float4(0.f, 0.f, 0.f, 0.f);
      ra1 = iv ? *(const float4*)(pp + 4) : make_float4(0.f, 0.f, 0.f, 0.f);
    }

    // ---- compute chunk c: 5 taps x (2mt x 2nt) x 3 terms; rolling B ----
    const int cb = (c + 1 < NC32) ? c + 1 : c;
#pragma unroll
    for (int k = 0; k < 5; ++k) {
      const s16x8 ah0 = *(const s16x8*)(bufC + abase_u + k * 40);
      const s16x8 al0 = *(const s16x8*)(bufC + 2720 + abase_u + k * 40);
      const s16x8 ah1 = *(const s16x8*)(bufC + abase_u + (16 + k) * 40);
      const s16x8 al1 = *(const s16x8*)(bufC + 2720 + abase_u + (16 + k) * 40);

      accf[0][0] = __builtin_amdgcn_mfma_f32_16x16x32_bf16(ah0, bh[k][0], accf[0][0], 0, 0, 0);
      accf[0][0] = __builtin_amdgcn_mfma_f32_16x16x32_bf16(al0, bh[k][0], accf[0][0], 0, 0, 0);
      accf[0][0] = __builtin_amdgcn_mfma_f32_16x16x32_bf16(ah0, bl[k][0], accf[0][0], 0, 0, 0);

      accf[0][1] = __builtin_amdgcn_mfma_f32_16x16x32_bf16(ah0, bh[k][1], accf[0][1], 0, 0, 0);
      accf[0][1] = __builtin_amdgcn_mfma_f32_16x16x32_bf16(al0, bh[k][1], accf[0][1], 0, 0, 0);
      accf[0][1] = __builtin_amdgcn_mfma_f32_16x16x32_bf16(ah0, bl[k][1], accf[0][1], 0, 0, 0);

      accf[1][0] = __builtin_amdgcn_mfma_f32_16x16x32_bf16(ah1, bh[k][0], accf[1][0], 0, 0, 0);
      accf[1][0] = __builtin_amdgcn_mfma_f32_16x16x32_bf16(al1, bh[k][0], accf[1][0], 0, 0, 0);
      accf[1][0] = __builtin_amdgcn_mfma_f32_16x16x32_bf16(ah1, bl[k][0], accf[1][0], 0, 0, 0);

      accf[1][1] = __builtin_amdgcn_mfma_f32_16x16x32_bf16(ah1, bh[k][1], accf[1][1], 0, 0, 0);
      accf[1][1] = __builtin_amdgcn_mfma_f32_16x16x32_bf16(al1, bh[k][1], accf[1][1], 0, 0, 0);
      accf[1][1] = __builtin_amdgcn_mfma_f32_16x16x32_bf16(ah1, bl[k][1], accf[1][1], 0, 0, 0);

      // rolling reload of this tap's frags for chunk cb (after last use)
      bh[k][0] = LDB(cb, k, ntg0, 0); bh[k][1] = LDB(cb, k, ntg1, 0);
      bl[k][0] = LDB(cb, k, ntg0, 1); bl[k][1] = LDB(cb, k, ntg1, 1);
    }

    // ---- promote chunk partial into fp64 ----
#pragma unroll
    for (int m = 0; m < 2; ++m)
#pragma unroll
      for (int n = 0; n < 2; ++n)
#pragma unroll
        for (int q = 0; q < 4; ++q) {
          accd[m][n][q] += (double)accf[m][n][q];
          accf[m][n][q] = 0.f;
        }
    __syncthreads();
    p ^= 1;
  }
#undef LDB

  // ---- y1 tile -> LDS (overlays A buffers; fenced by loop-final sync) ----
  // C/D layout: col = lane&15, row = (lane>>4)*4 + reg
  double* y1s = dsm;
#pragma unroll
  for (int m = 0; m < 2; ++m)
#pragma unroll
    for (int n = 0; n < 2; ++n)
#pragma unroll
      for (int q = 0; q < 4; ++q) {
        const int t = 32 * wr + 16 * m + lg * 4 + q;
        if (t < T1) y1s[t * 64 + 32 * wc + 16 * n + lr] = accd[m][n][q];
      }
  __syncthreads();

  // ---- fp64 LIF scan on wave 0 + ballot bit-pack ----
  if (tid < 64) {
    const int o = ow * 64 + tid;
    const bool valid = o < HID;
    const double bias = valid ? (double)b1v[o] : 0.0;
    u32* bits = gbits + (size_t)b * 510;
    double mem = 0.0;
    for (int t = 0; t < T1; ++t) {
      const double x = y1s[t * 64 + tid] + bias;
      const double reset = (mem > 1.0) ? 1.0 : 0.0;
      mem = __dsub_rn(__dadd_rn(__dmul_rn(0.9, mem), x), reset);
      const unsigned long long mk = __ballot(valid && (mem > 1.0));
      if (tid == 0)  bits[t * 10 + 2 * ow]     = (u32)mk;
      if (tid == 32) bits[t * 10 + 2 * ow + 1] = (u32)(mk >> 32);
    }
  }
}

// ===========================================================================
// Fallback layer-1 (fp32, gauss in-kernel) — round-1/2 proven path.
// ===========================================================================
__device__ __forceinline__ void layer1_tile_g(
    int b, int ow, int tid,
    const float* __restrict__ data, const float* __restrict__ W1,
    const float* __restrict__ P1, const float* __restrict__ b1v,
    double* __restrict__ dsm, u32* __restrict__ bits)
{
  float* Bsf = (float*)dsm;
  float* As  = (float*)dsm + 2880;

  const int ty = tid >> 5;
  const int tx = tid & 31;
  const int r0 = ty << 3;
  const int c0 = tx << 1;

  const float* abase = data + (size_t)b * (TT * CIN);

  const int slot = tid >> 2;
  const int pair = tid & 3;
  const int tp   = slot - 5;

  const int isub = tid & 7;
  const int oA = tid >> 3;
  const int oB = oA + 32;
  const int boA = ow * 64 + oA;
  const int boB = ow * 64 + oB;
  const bool vB = boB < HID;

  double acc[8][2];
#pragma unroll
  for (int r = 0; r < 8; ++r) { acc[r][0] = 0.0; acc[r][1] = 0.0; }

  float2 aA = make_float2(0.f, 0.f);
  float wA = 0.f, pA = 0.f, wB = 0.f, pB = 0.f;
  if (tid < 220 && tp >= 0)
    aA = *(const float2*)(abase + (size_t)tp * CIN + 2 * pair);
  wA = W1[(size_t)boA * CIN + isub];
  pA = P1[(size_t)boA * CIN + isub];
  if (vB) {
    wB = W1[(size_t)boB * CIN + isub];
    pB = P1[(size_t)boB * CIN + isub];
  }

  for (int i0 = 0; i0 < CIN; i0 += 8) {
    if (tid < 220) {
      As[(2 * pair) * 80 + slot]     = aA.x;
      As[(2 * pair + 1) * 80 + slot] = aA.y;
    }
    {
      const float c  = pA + 2.0f;
      const float E0 = __expf(-0.125f * c * c);
      const float U  = __expf(0.25f * c);
      const float u2 = U * U;
      const float e0 = E0;
      const float e1 = E0 * U * EK1f;
      const float e2 = E0 * u2 * EK2f;
      const float e3 = E0 * (u2 * U) * EK3f;
      const float e4 = E0 * (u2 * u2) * EK4f;
      const float inv = 1.0f / (((((e0 + e1) + e2) + e3) + e4) + 1e-7f);
      float* bp = Bsf + isub * 72 + oA;
      bp[0]    = wA * (e0 * inv);
      bp[576]  = wA * (e1 * inv);
      bp[1152] = wA * (e2 * inv);
      bp[1728] = wA * (e3 * inv);
      bp[2304] = wA * (e4 * inv);
    }
    {
      const float c  = pB + 2.0f;
      const float E0 = __expf(-0.125f * c * c);
      const float U  = __expf(0.25f * c);
      const float u2 = U * U;
      const float e0 = E0;
      const float e1 = E0 * U * EK1f;
      const float e2 = E0 * u2 * EK2f;
      const float e3 = E0 * (u2 * U) * EK3f;
      const float e4 = E0 * (u2 * u2) * EK4f;
      const float inv = 1.0f / (((((e0 + e1) + e2) + e3) + e4) + 1e-7f);
      float* bp = Bsf + isub * 72 + oB;
      bp[0]    = wB * (e0 * inv);
      bp[576]  = wB * (e1 * inv);
      bp[1152] = wB * (e2 * inv);
      bp[1728] = wB * (e3 * inv);
      bp[2304] = wB * (e4 * inv);
    }
    __syncthreads();

    const int i0n = i0 + 8;
    if (i0n < CIN) {
      if (tid < 220 && tp >= 0)
        aA = *(const float2*)(abase + (size_t)tp * CIN + i0n + 2 * pair);
      wA = W1[(size_t)boA * CIN + i0n + isub];
      pA = P1[(size_t)boA * CIN + i0n + isub];
      if (vB) {
        wB = W1[(size_t)boB * CIN + i0n + isub];
        pB = P1[(size_t)boB * CIN + i0n + isub];
      }
    }

    float accf[8][2];
#pragma unroll
    for (int r = 0; r < 8; ++r) { accf[r][0] = 0.f; accf[r][1] = 0.f; }
#pragma unroll
    for (int kk = 0; kk < 8; ++kk) {
      const float* ap = &As[kk * 80 + r0];
      const float4 a0 = *(const float4*)(ap);
      const float4 a1 = *(const float4*)(ap + 4);
      const float4 a2 = *(const float4*)(ap + 8);
      float av[12];
      av[0] = a0.x; av[1] = a0.y; av[2]  = a0.z; av[3]  = a0.w;
      av[4] = a1.x; av[5] = a1.y; av[6]  = a1.z; av[7]  = a1.w;
      av[8] = a2.x; av[9] = a2.y; av[10] = a2.z; av[11] = a2.w;
      float bv[KS][2];
#pragma unroll
      for (int k = 0; k < KS; ++k) {
        const float2 bb = *(const float2*)&Bsf[(k * 8 + kk) * 72 + c0];
        bv[k][0] = bb.x; bv[k][1] = bb.y;
      }
#pragma unroll
      for (int k = 0; k < KS; ++k)
#pragma unroll
        for (int r = 0; r < 8; ++r) {
          accf[r][0] = fmaf(av[r + k], bv[k][0], accf[r][0]);
          accf[r][1] = fmaf(av[r + k], bv[k][1], accf[r][1]);
        }
    }
#pragma unroll
    for (int r = 0; r < 8; ++r) {
      acc[r][0] += (double)accf[r][0];
      acc[r][1] += (double)accf[r][1];
    }
    __syncthreads();
  }

  double* y1s = dsm;
#pragma unroll
  for (int r = 0; r < 8; ++r) {
    const int t = r0 + r;
    if (t < T1) {
      y1s[t * 64 + c0]     = acc[r][0];
      y1s[t * 64 + c0 + 1] = acc[r][1];
    }
  }
  __syncthreads();

  if (tid < 64) {
    const int o = ow * 64 + tid;
    const bool valid = o < HID;
    const double bias = valid ? (double)b1v[o] : 0.0;
    double mem = 0.0;
    for (int t = 0; t < T1; ++t) {
      const double x = y1s[t * 64 + tid] + bias;
      const double reset = (mem > 1.0) ? 1.0 : 0.0;
      mem = __dsub_rn(__dadd_rn(__dmul_rn(0.9, mem), x), reset);
      const unsigned long long mk = __ballot(valid && (mem > 1.0));
      if (tid == 0)  bits[t * 10 + 2 * ow]     = (u32)mk;
      if (tid == 32) bits[t * 10 + 2 * ow + 1] = (u32)(mk >> 32);
    }
  }
  __syncthreads();
}

// ---------------------------------------------------------------------------
// Layer-2 conv + LIF2 (fp32), spike bits already in LDS at smem+15000.
// ---------------------------------------------------------------------------
__device__ __forceinline__ void layer2_lif2(
    int b, int tid, float* smem,
    const float* __restrict__ W2, const float* __restrict__ P2,
    const float* __restrict__ b2, float* __restrict__ out)
{
  float* K2s = smem;
  const u32* lbits = (const u32*)(smem + 15000);
  float* y2s = smem + 15510;

  for (int idx = tid; idx < NOUT * HID; idx += 256) {
    const int o = idx / HID, i = idx % HID;
    const float w = W2[idx], p = P2[idx];
    const float c = p + 2.0f;
    float e[KS], s = 0.f;
#pragma unroll
    for (int k = 0; k < KS; ++k) {
      const float d = ((float)k - c) * 0.5f;
      e[k] = __expf(-0.5f * d * d);
      s += e[k];
    }
    const float denom = s + 1e-7f;
#pragma unroll
    for (int k = 0; k < KS; ++k)
      K2s[(o * KS + k) * HID + i] = w * (e[k] / denom);
  }
  __syncthreads();                    // also fences lbits population

  for (int task = tid; task < T2 * NOUT; task += 256) {
    const int t2 = task / NOUT, o = task % NOUT;
    float acc = b2[o];
#pragma unroll
    for (int k = 0; k < KS; ++k) {
      const int tp = t2 + k - KS;
      if (tp < 0 || tp >= T1) continue;
      const float* kr = K2s + (o * KS + k) * HID;
      const u32* br = lbits + tp * 10;
      for (int i = 0; i < HID; ++i)
        acc = fmaf((float)((br[i >> 5] >> (i & 31)) & 1u), kr[i], acc);
    }
    y2s[task] = acc;
  }
  __syncthreads();

  if (tid < NOUT) {
    float mem = 0.f;
    for (int t = 0; t < T2; ++t) {
      const float x = y2s[t * NOUT + tid];
      const float reset = (mem > 1.0f) ? 1.0f : 0.0f;
      mem = __fsub_rn(__fadd_rn(__fmul_rn(0.9f, mem), x), reset);
      out[(size_t)t * (BSZ * NOUT) + b * NOUT + tid] = (mem > 1.0f) ? 1.0f : 0.0f;
      out[(size_t)T2 * BSZ * NOUT + (size_t)t * (BSZ * NOUT) + b * NOUT + tid] = mem;
    }
  }
}

// ---------------- split-path kernels ----------------------------------------
__global__ __launch_bounds__(256) void snn_l1(
    const float* __restrict__ data, const float* __restrict__ W1,
    const float* __restrict__ P1, const float* __restrict__ b1v,
    u32* __restrict__ gbits)
{
  __shared__ double dsm[3264];
  const int ow = blockIdx.x, b = blockIdx.y;
  layer1_tile_g(b, ow, threadIdx.x, data, W1, P1, b1v, dsm,
                gbits + (size_t)b * 510);
}

__global__ __launch_bounds__(256) void snn_l2k(
    const u32* __restrict__ gbits,
    const float* __restrict__ W2, const float* __restrict__ P2,
    const float* __restrict__ b2, float* __restrict__ out)
{
  __shared__ float smem[16030];
  const int b = blockIdx.x, tid = threadIdx.x;
  u32* lbits = (u32*)(smem + 15000);
  for (int i = tid; i < 510; i += 256) lbits[i] = gbits[(size_t)b * 510 + i];
  layer2_lif2(b, tid, smem, W2, P2, b2, out);
}

// ---------------- zero-workspace fallback -----------------------------------
__global__ __launch_bounds__(256) void snn_mono(
    const float* __restrict__ data, const float* __restrict__ W1,
    const float* __restrict__ P1, const float* __restrict__ b1v,
    const float* __restrict__ W2, const float* __restrict__ P2,
    const float* __restrict__ b2, float* __restrict__ out)
{
  __shared__ double dsm[8015];
  const int b = blockIdx.x, tid = threadIdx.x;
  u32* lbits = (u32*)((float*)dsm + 15000);
  for (int ow = 0; ow < 5; ++ow)
    layer1_tile_g(b, ow, tid, data, W1, P1, b1v, dsm, lbits);
  layer2_lif2(b, tid, (float*)dsm, W2, P2, b2, out);
}

// ---------------- launcher --------------------------------------------------
extern "C" void kernel_launch(void* const* d_in, const int* in_sizes, int n_in,
                              void* d_out, int out_size, void* d_ws, size_t ws_size,
                              hipStream_t stream) {
  const float* data = (const float*)d_in[0];
  const float* W1   = (const float*)d_in[1];
  const float* P1   = (const float*)d_in[2];
  const float* b1v  = (const float*)d_in[3];
  const float* W2   = (const float*)d_in[4];
  const float* P2   = (const float*)d_in[5];
  const float* b2   = (const float*)d_in[6];
  float* out = (float*)d_out;

  const size_t BITS_BYTES = (size_t)BSZ * T1 * 10 * sizeof(u32);   // 261,120 B
  const size_t K1_OFF = 262144;                                     // 256 KiB
  const size_t K1BF_BYTES = (size_t)5 * NC32 * KFRAG_U * 2;         // 14,950,400
  const size_t NEED_M = K1_OFF + K1BF_BYTES;                        // ~15.2 MB

  if (ws_size >= NEED_M) {
    u32* gbits = (u32*)d_ws;
    u16* K1bf  = (u16*)((char*)d_ws + K1_OFF);
    snn_prepm<<<dim3(NC32, 5), 256, 0, stream>>>(W1, P1, K1bf);
    snn_l1m<<<640, 256, 0, stream>>>(data, K1bf, b1v, gbits);
    snn_l2k<<<BSZ, 256, 0, stream>>>(gbits, W2, P2, b2, out);
  } else if (ws_size >= BITS_BYTES) {
    u32* gbits = (u32*)d_ws;
    snn_l1<<<dim3(5, BSZ), 256, 0, stream>>>(data, W1, P1, b1v, gbits);
    snn_l2k<<<BSZ, 256, 0, stream>>>(gbits, W2, P2, b2, out);
  } else {
    snn_mono<<<BSZ, 256, 0, stream>>>(data, W1, P1, b1v, W2, P2, b2, out);
  }
}